// Round 10
// baseline (556.556 us; speedup 1.0000x reference)
//
#include <hip/hip_runtime.h>
#include <hip/hip_bf16.h>
#include <cmath>

#define HH 128
#define WW 128
#define HWSZ (HH*WW)
#define BB 4

typedef __attribute__((ext_vector_type(8))) short short8;
typedef _Float16 half8 __attribute__((ext_vector_type(8)));
typedef __attribute__((ext_vector_type(16))) float f32x16;

__device__ __forceinline__ ushort f16_rn(float f) {
    _Float16 h = (_Float16)f;
    return __builtin_bit_cast(ushort, h);
}

// ---------------------------------------------------------------------------
// Weight prep -> FRAGMENT-READY fp16 (single plane):
//   dst = kc*32*OCpad + ks*16*OCpad + oc*16 + lhi*8 + j
// ---------------------------------------------------------------------------
__global__ __launch_bounds__(256) void prep_wf_k(const float* __restrict__ w,
                                                 ushort* __restrict__ whiF,
                                                 int OC, int K, int OCpad, int KPAD) {
    int idx = blockIdx.x * 256 + threadIdx.x;
    if (idx >= OCpad * KPAD) return;
    int oc = idx / KPAD, k = idx - oc * KPAD;
    float v = (oc < OC && k < K) ? w[(size_t)oc * K + k] : 0.f;
    const int kc = k >> 5, r = k & 31;
    const int ks = r >> 4, lhi = (r >> 3) & 1, j = r & 7;
    const size_t dst = (size_t)kc * 32 * OCpad + ks * 16 * OCpad + oc * 16 + lhi * 8 + j;
    whiF[dst] = f16_rn(v);
}

// ---------------------------------------------------------------------------
// Deform weight prep -> fragment-ready fp16 (k-major kidx = k9*64 + c).
// ---------------------------------------------------------------------------
__global__ __launch_bounds__(256) void prep_wdf_k(const float* __restrict__ w,
                                                  ushort* __restrict__ whiF) {
    int idx = blockIdx.x * 256 + threadIdx.x;
    if (idx >= 64 * 576) return;
    int oc = idx / 576, rem = idx - oc * 576;
    int k9 = rem / 64, c = rem & 63;
    float v = w[(size_t)oc * 576 + c * 9 + k9];
    const int hv = c >> 5, r = c & 31;
    const int ks = r >> 4, lhi = (r >> 3) & 1, j = r & 7;
    const size_t dst = (size_t)((k9 * 2 + hv) * 2 + ks) * 1024 + oc * 16 + lhi * 8 + j;
    whiF[dst] = f16_rn(v);
}

// ---------------------------------------------------------------------------
// Input concat -> fp16 planes [b][132][H][W] (ch 130,131 zero).
// ---------------------------------------------------------------------------
__global__ __launch_bounds__(256) void cvt_in_k(const float* __restrict__ xfw,
                                                const float* __restrict__ xcur,
                                                const float* __restrict__ flow,
                                                ushort* __restrict__ concatP) {
    int idx = blockIdx.x * 256 + threadIdx.x;
    if (idx >= BB * 132 * HWSZ) return;
    int b = idx / (132 * HWSZ);
    int rem = idx - b * 132 * HWSZ;
    int c = rem / HWSZ, pix = rem - c * HWSZ;
    float v = 0.f;
    if (c < 64)       v = xfw [((size_t)b * 64 + c)       * HWSZ + pix];
    else if (c < 128) v = xcur[((size_t)b * 64 + c - 64)  * HWSZ + pix];
    else if (c < 130) v = flow[((size_t)b * 2  + c - 128) * HWSZ + pix];
    concatP[idx] = f16_rn(v);
}

// ---------------------------------------------------------------------------
// Pack x into gather-friendly float4: xP[b][dg][pix]
// ---------------------------------------------------------------------------
__global__ __launch_bounds__(256) void pack_x_k(const float* __restrict__ x,
                                                float4* __restrict__ xP) {
    int idx = blockIdx.x * 256 + threadIdx.x;
    if (idx >= BB * 16 * HWSZ) return;
    int b = idx / (16 * HWSZ);
    int rem = idx - b * 16 * HWSZ;
    int dg = rem / HWSZ, pix = rem - dg * HWSZ;
    const float* src = x + ((size_t)b * 64 + dg * 4) * HWSZ + pix;
    float4 v;
    v.x = src[0];
    v.y = src[HWSZ];
    v.z = src[2 * HWSZ];
    v.w = src[3 * HWSZ];
    xP[idx] = v;
}

// ---------------------------------------------------------------------------
// conv0/1/2: single-fp16 implicit-GEMM, 2-ROW tile (64 oc x 256 px).
// 512 threads = 8 waves (2M x 4N); each wave 32oc x 64px (2 pg).
// ---------------------------------------------------------------------------
template<int IC, int KPAD>
__global__ __launch_bounds__(512, 4) void conv_n256(
    const ushort* __restrict__ inP, const ushort* __restrict__ whiF,
    const float* __restrict__ bias, ushort* __restrict__ outP)
{
    constexpr int NCHUNK = KPAD / 32;
    constexpr int LDK = 40;
    constexpr int NBLK = BB * 64;      // 256 blocks (2 rows each)
    constexpr int PER = NBLK / 8;

    __shared__ ushort iB[2][256 * LDK];   // 40 KB

    const int tid = threadIdx.x;
    const int id  = blockIdx.x;
    const int orig = (id & 7) * PER + (id >> 3);   // XCD-chunked bijective
    const int b   = orig >> 6;
    const int y0r = (orig & 63) * 2;

    const int wave = tid >> 6, lane = tid & 63;
    const int wm = wave >> 2, wn = wave & 3;
    const int l31 = lane & 31, lhi = lane >> 5;

    const int px2 = tid & 255;                     // staging slot (row*128+px)
    const int spx = px2 & 127;
    const int srow = __builtin_amdgcn_readfirstlane((tid >> 7) & 1);
    const int skh  = __builtin_amdgcn_readfirstlane(tid >> 8);   // 16-k half

    f32x16 acc[2] = {};
    ushort pb[16];

    auto FETCH = [&](int kc) {
        #pragma unroll
        for (int j = 0; j < 16; ++j) {
            const int k  = kc * 32 + skh * 16 + j;   // wave-uniform
            const int ic = k / 9;
            const int kk = k - ic * 9;
            const int ky = kk / 3;
            const int kx = kk - ky * 3;
            const int gyy = y0r + srow + ky - 1;     // wave-uniform
            const int gx = spx + kx - 1;             // per-lane
            ushort u = 0;
            if ((unsigned)gyy < (unsigned)HH && (unsigned)gx < (unsigned)WW)
                u = inP[((size_t)b * IC + ic) * HWSZ + gyy * WW + gx];
            pb[j] = u;
        }
    };
    auto WRITE = [&](int buf) {
        short8 w0v, w1v;
        #pragma unroll
        for (int j = 0; j < 8; ++j) { w0v[j] = (short)pb[j]; w1v[j] = (short)pb[8 + j]; }
        *(short8*)&iB[buf][px2 * LDK + skh * 16]     = w0v;
        *(short8*)&iB[buf][px2 * LDK + skh * 16 + 8] = w1v;
    };

    FETCH(0);
    WRITE(0);

    for (int kc = 0; kc < NCHUNK; ++kc) {
        __syncthreads();
        const int cur = kc & 1;

        half8 af[2];
        #pragma unroll
        for (int ks = 0; ks < 2; ++ks) {
            const size_t ga = (size_t)kc * 32 * 64 + (size_t)ks * 16 * 64
                            + (wm * 32 + l31) * 16 + lhi * 8;
            af[ks] = __builtin_bit_cast(half8, *(const short8*)&whiF[ga]);
        }
        if (kc + 1 < NCHUNK) FETCH(kc + 1);

        #pragma unroll
        for (int ks = 0; ks < 2; ++ks) {
            const int koff = ks * 16 + lhi * 8;
            #pragma unroll
            for (int pg = 0; pg < 2; ++pg) {
                const int ib = (pg * 128 + wn * 32 + l31) * LDK + koff;
                const half8 bh = __builtin_bit_cast(half8, *(const short8*)&iB[cur][ib]);
                acc[pg] = __builtin_amdgcn_mfma_f32_32x32x16_f16(af[ks], bh, acc[pg], 0, 0, 0);
            }
        }

        if (kc + 1 < NCHUNK) WRITE(1 - cur);
    }

    const int px = wn * 32 + l31;
    #pragma unroll
    for (int pg = 0; pg < 2; ++pg) {
        const int y = y0r + pg;
        #pragma unroll
        for (int r = 0; r < 16; ++r) {
            const int oc = wm * 32 + (r & 3) + 8 * (r >> 2) + 4 * lhi;
            float v = acc[pg][r] + bias[oc];
            v = v >= 0.f ? v : 0.1f * v;
            outP[((size_t)b * 64 + oc) * HWSZ + y * WW + px] = f16_rn(v);
        }
    }
}

// ---------------------------------------------------------------------------
// conv3: single-fp16, M-tile 256 (NG=4) x 128 px, NGY=2, 512 threads.
// ---------------------------------------------------------------------------
template<int KPAD>
__global__ __launch_bounds__(512, 4) void conv_m512(
    const ushort* __restrict__ inP, const ushort* __restrict__ whiF,
    const float* __restrict__ bias, float* __restrict__ outF,
    const float* __restrict__ flow)
{
    constexpr int NCHUNK = KPAD / 32;
    constexpr int LDK = 40;
    constexpr int OCPAD = 512;
    constexpr int NBLK = BB * HH * 2;  // 1024
    constexpr int PER = NBLK / 8;

    __shared__ ushort iB[2][128 * LDK];   // 20 KB

    const int tid = threadIdx.x;
    const int id  = blockIdx.x;
    const int orig = (id & 7) * PER + (id >> 3);
    const int row = orig >> 1, gy = orig & 1;
    const int b = row >> 7, y = row & 127;
    const int o0 = gy * 256;

    const int wave = tid >> 6, lane = tid & 63;
    const int wm = wave >> 2, wn = wave & 3;
    const int l31 = lane & 31, lhi = lane >> 5;
    const int spx = tid & 127;
    const int sko = __builtin_amdgcn_readfirstlane(tid >> 7);

    f32x16 acc[4] = {};
    ushort pb[8];

    auto FETCH4 = [&](int kc, int j0) {
        #pragma unroll
        for (int j = j0; j < j0 + 4; ++j) {
            const int k  = kc * 32 + sko * 8 + j;
            const int ic = k / 9;
            const int kk = k - ic * 9;
            const int ky = kk / 3;
            const int kx = kk - ky * 3;
            const int gyy = y + ky - 1;
            const int gx = spx + kx - 1;
            ushort u = 0;
            if ((unsigned)gyy < (unsigned)HH && (unsigned)gx < (unsigned)WW)
                u = inP[((size_t)b * 64 + ic) * HWSZ + gyy * WW + gx];
            pb[j] = u;
        }
    };
    auto WRITE = [&](int buf) {
        short8 pw;
        #pragma unroll
        for (int j = 0; j < 8; ++j) pw[j] = (short)pb[j];
        *(short8*)&iB[buf][spx * LDK + sko * 8] = pw;
    };

    FETCH4(0, 0); FETCH4(0, 4);
    WRITE(0);

    for (int kc = 0; kc < NCHUNK; ++kc) {
        __syncthreads();
        const int cur = kc & 1;
        const bool more = (kc + 1 < NCHUNK);

        #pragma unroll
        for (int ks = 0; ks < 2; ++ks) {
            half8 af[4];
            #pragma unroll
            for (int mg = 0; mg < 4; ++mg) {
                const size_t ga = (size_t)kc * 32 * OCPAD + (size_t)ks * 16 * OCPAD
                                + (o0 + wm * 128 + mg * 32 + l31) * 16 + lhi * 8;
                af[mg] = __builtin_bit_cast(half8, *(const short8*)&whiF[ga]);
            }
            if (more) FETCH4(kc + 1, ks * 4);

            const int koff = ks * 16 + lhi * 8;
            const int ib = (wn * 32 + l31) * LDK + koff;
            const half8 bh = __builtin_bit_cast(half8, *(const short8*)&iB[cur][ib]);
            #pragma unroll
            for (int mg = 0; mg < 4; ++mg)
                acc[mg] = __builtin_amdgcn_mfma_f32_32x32x16_f16(af[mg], bh, acc[mg], 0, 0, 0);
        }

        if (more) WRITE(1 - cur);
    }

    const int px = wn * 32 + l31;
    #pragma unroll
    for (int mg = 0; mg < 4; ++mg) {
        #pragma unroll
        for (int r = 0; r < 16; ++r) {
            const int oc = o0 + wm * 128 + mg * 32 + (r & 3) + 8 * (r >> 2) + 4 * lhi;
            if (oc < 432) {
                float v = acc[mg][r] + bias[oc];
                float res;
                if (oc < 288) {
                    const float fl = flow[(((size_t)b * 2 + ((oc & 1) ? 0 : 1)) * HH + y) * WW + px];
                    res = 10.f * tanhf(v) + fl;
                } else {
                    res = 1.f / (1.f + expf(-v));
                }
                outF[((size_t)b * 432 + oc) * HWSZ + y * WW + px] = res;
            }
        }
    }
}

// ---------------------------------------------------------------------------
// MFMA deformable conv v8: occupancy-optimized. 32 px/block, 2048 blocks
// (= 8 blocks/CU exactly), 256 threads = 4 waves, each wave one
// (k9-half x hv) quadrant of the K reduction. Every (pix,dg,k9) is still
// sampled exactly once per block. Two-phase LDS reduction (2 buffers, 17KB)
// keeps 8 blocks/CU resident -> ~100% wave occupancy to hide gather latency.
// ---------------------------------------------------------------------------
__global__ __launch_bounds__(256, 8) void deform_v8(
    const float4* __restrict__ xP, const float* __restrict__ offm,
    const ushort* __restrict__ wdfh,
    const float* __restrict__ bias, float* __restrict__ outp)
{
    __shared__ float red[2][64][33];   // 16.9 KB

    const int tid = threadIdx.x;
    const int id  = blockIdx.x;
    const int orig = (id & 7) * 256 + (id >> 3);   // 2048 blocks, bijective
    const int x0 = (orig & 3) * 32;
    const int rl = orig >> 2;
    const int y = rl & 127, b = rl >> 7;

    const int wave = tid >> 6, lane = tid & 63;
    const int l31 = lane & 31, lhi = lane >> 5;
    const int k9h = wave >> 1;         // k9 half: 0 -> [0,5), 1 -> [5,9)
    const int hv  = wave & 1;          // dg half

    const int xp  = x0 + l31;          // this lane's pixel (B column)
    const int pix = y * WW + xp;
    const float* offb = offm + (size_t)b * 432 * HWSZ;
    const float fy = (float)y, fx = (float)xp;

    f32x16 acc[2] = {};

    const int k9lo = k9h ? 5 : 0;
    const int k9hi = k9h ? 9 : 5;
    for (int k9 = k9lo; k9 < k9hi; ++k9) {
        const float kyf = (float)(k9 / 3 - 1);
        const float kxf = (float)(k9 % 3 - 1);
        #pragma unroll
        for (int ks = 0; ks < 2; ++ks) {
            short8 bfs;
            #pragma unroll
            for (int d2 = 0; d2 < 2; ++d2) {
                const int dg = hv * 8 + ks * 4 + lhi * 2 + d2;
                const float dy = offb[(size_t)(dg * 18 + k9 * 2)     * HWSZ + pix];
                const float dx = offb[(size_t)(dg * 18 + k9 * 2 + 1) * HWSZ + pix];
                const float mk = offb[(size_t)(288 + dg * 9 + k9)    * HWSZ + pix];
                const float py = dy + kyf + fy;
                const float px = dx + kxf + fx;
                const float y0f = floorf(py), x0f = floorf(px);
                const float ly = py - y0f, lx = px - x0f;
                const int yi = (int)y0f, xi = (int)x0f;
                const float w00 = (1.f - ly) * (1.f - lx), w01 = (1.f - ly) * lx;
                const float w10 = ly * (1.f - lx),         w11 = ly * lx;
                const bool vy0 = (unsigned)yi < (unsigned)HH, vy1 = (unsigned)(yi + 1) < (unsigned)HH;
                const bool vx0 = (unsigned)xi < (unsigned)WW, vx1 = (unsigned)(xi + 1) < (unsigned)WW;
                const float f00 = (vy0 && vx0) ? w00 * mk : 0.f;
                const float f01 = (vy0 && vx1) ? w01 * mk : 0.f;
                const float f10 = (vy1 && vx0) ? w10 * mk : 0.f;
                const float f11 = (vy1 && vx1) ? w11 * mk : 0.f;
                const int cy0 = min(max(yi, 0), HH - 1), cy1 = min(max(yi + 1, 0), HH - 1);
                const int cx0 = min(max(xi, 0), WW - 1), cx1 = min(max(xi + 1, 0), WW - 1);
                const float4* xg = xP + (size_t)(b * 16 + dg) * HWSZ;
                const float4 c00 = xg[cy0 * WW + cx0], c01 = xg[cy0 * WW + cx1];
                const float4 c10 = xg[cy1 * WW + cx0], c11 = xg[cy1 * WW + cx1];
                bfs[d2 * 4 + 0] = (short)f16_rn(f00 * c00.x + f01 * c01.x + f10 * c10.x + f11 * c11.x);
                bfs[d2 * 4 + 1] = (short)f16_rn(f00 * c00.y + f01 * c01.y + f10 * c10.y + f11 * c11.y);
                bfs[d2 * 4 + 2] = (short)f16_rn(f00 * c00.z + f01 * c01.z + f10 * c10.z + f11 * c11.z);
                bfs[d2 * 4 + 3] = (short)f16_rn(f00 * c00.w + f01 * c01.w + f10 * c10.w + f11 * c11.w);
            }
            const half8 bf = __builtin_bit_cast(half8, bfs);
            const size_t abase = (size_t)((k9 * 2 + hv) * 2 + ks) * 1024 + l31 * 16 + lhi * 8;
            #pragma unroll
            for (int mg = 0; mg < 2; ++mg) {
                const half8 ah = __builtin_bit_cast(half8, *(const short8*)&wdfh[abase + mg * 512]);
                acc[mg] = __builtin_amdgcn_mfma_f32_32x32x16_f16(ah, bf, acc[mg], 0, 0, 0);
            }
        }
    }

    // ---- two-phase cross-wave reduction: (0+2) and (1+3), then 0+1 ----
    if (wave >= 2) {
        #pragma unroll
        for (int mg = 0; mg < 2; ++mg)
            #pragma unroll
            for (int r = 0; r < 16; ++r)
                red[wave - 2][lane][mg * 16 + r] = acc[mg][r];
    }
    __syncthreads();
    if (wave < 2) {
        #pragma unroll
        for (int mg = 0; mg < 2; ++mg)
            #pragma unroll
            for (int r = 0; r < 16; ++r)
                acc[mg][r] += red[wave][lane][mg * 16 + r];
    }
    __syncthreads();
    if (wave == 1) {
        #pragma unroll
        for (int mg = 0; mg < 2; ++mg)
            #pragma unroll
            for (int r = 0; r < 16; ++r)
                red[0][lane][mg * 16 + r] = acc[mg][r];
    }
    __syncthreads();
    if (wave == 0) {
        #pragma unroll
        for (int mg = 0; mg < 2; ++mg)
            #pragma unroll
            for (int r = 0; r < 16; ++r) {
                const int oc = mg * 32 + (r & 3) + 8 * (r >> 2) + 4 * lhi;
                const float v = acc[mg][r] + red[0][lane][mg * 16 + r] + bias[oc];
                outp[(((size_t)b * 64 + oc) * HH + y) * WW + xp] = v;
            }
    }
}

// ---------------------------------------------------------------------------
extern "C" void kernel_launch(void* const* d_in, const int* in_sizes, int n_in,
                              void* d_out, int out_size, void* d_ws, size_t ws_size,
                              hipStream_t stream) {
    const float* x    = (const float*)d_in[0];
    const float* xfw  = (const float*)d_in[1];
    const float* xcur = (const float*)d_in[2];
    const float* flow = (const float*)d_in[3];
    const float* w0   = (const float*)d_in[4];
    const float* b0   = (const float*)d_in[5];
    const float* w1   = (const float*)d_in[6];
    const float* b1   = (const float*)d_in[7];
    const float* w2   = (const float*)d_in[8];
    const float* b2   = (const float*)d_in[9];
    const float* w3   = (const float*)d_in[10];
    const float* b3   = (const float*)d_in[11];
    const float* wdcn = (const float*)d_in[12];
    const float* bdcn = (const float*)d_in[13];
    float* out = (float*)d_out;

    // workspace (aliased; stream order makes it safe):
    //   [0, 113.2MB) offm fp32 (concatP fp16 17.3MB aliases head, dead before conv3)
    //   h0P fp16 8.4MB (conv2 reuses = h2P) | h1P fp16 8.4MB |
    //   xP float4 16.8MB | single-plane fp16 weights ~1MB
    float* offm     = (float*)d_ws;
    ushort* concatP = (ushort*)d_ws;
    ushort* h0P     = (ushort*)((char*)d_ws + (size_t)BB * 432 * HWSZ * 4);
    ushort* h1P     = h0P + (size_t)BB * 64 * HWSZ;
    float4* xP      = (float4*)(h1P + (size_t)BB * 64 * HWSZ);
    ushort* wp      = (ushort*)(xP + (size_t)BB * 16 * HWSZ);
    ushort* wdh = wp;
    ushort* w0h = wdh + 64 * 576;
    ushort* w1h = w0h + 64 * 1184;
    ushort* w2h = w1h + 64 * 576;
    ushort* w3h = w2h + 64 * 576;          // 512*576
    ushort* h2P = h0P;                     // conv2 output reuses h0P

    prep_wf_k<<<dim3((64 * 1184 + 255) / 256), dim3(256), 0, stream>>>(w0, w0h, 64, 1170, 64, 1184);
    prep_wf_k<<<dim3((64 * 576 + 255) / 256),  dim3(256), 0, stream>>>(w1, w1h, 64, 576, 64, 576);
    prep_wf_k<<<dim3((64 * 576 + 255) / 256),  dim3(256), 0, stream>>>(w2, w2h, 64, 576, 64, 576);
    prep_wf_k<<<dim3((512 * 576 + 255) / 256), dim3(256), 0, stream>>>(w3, w3h, 432, 576, 512, 576);
    prep_wdf_k<<<dim3((64 * 576 + 255) / 256), dim3(256), 0, stream>>>(wdcn, wdh);
    cvt_in_k<<<dim3((BB * 132 * HWSZ + 255) / 256), dim3(256), 0, stream>>>(xfw, xcur, flow, concatP);

    conv_n256<132, 1184><<<dim3(BB * 64), dim3(512), 0, stream>>>(concatP, w0h, b0, h0P);
    conv_n256<64, 576><<<dim3(BB * 64), dim3(512), 0, stream>>>(h0P, w1h, b1, h1P);
    conv_n256<64, 576><<<dim3(BB * 64), dim3(512), 0, stream>>>(h1P, w2h, b2, h2P);
    pack_x_k<<<dim3((BB * 16 * HWSZ + 255) / 256), dim3(256), 0, stream>>>(x, xP);
    conv_m512<576><<<dim3(BB * HH * 2), dim3(512), 0, stream>>>(h2P, w3h, b3, offm, flow);

    deform_v8<<<dim3(2048), dim3(256), 0, stream>>>(xP, offm, wdh, bdcn, out);
}

// Round 11
// 394.568 us; speedup vs baseline: 1.4105x; 1.4105x over previous
//
#include <hip/hip_runtime.h>
#include <hip/hip_bf16.h>
#include <cmath>

#define HH 128
#define WW 128
#define HWSZ (HH*WW)
#define BB 4

typedef __attribute__((ext_vector_type(8))) short short8;
typedef _Float16 half8 __attribute__((ext_vector_type(8)));
typedef __attribute__((ext_vector_type(16))) float f32x16;

__device__ __forceinline__ ushort f16_rn(float f) {
    _Float16 h = (_Float16)f;
    return __builtin_bit_cast(ushort, h);
}

// ---------------------------------------------------------------------------
// Weight prep -> FRAGMENT-READY fp16 (single plane):
//   dst = kc*32*OCpad + ks*16*OCpad + oc*16 + lhi*8 + j
// ---------------------------------------------------------------------------
__global__ __launch_bounds__(256) void prep_wf_k(const float* __restrict__ w,
                                                 ushort* __restrict__ whiF,
                                                 int OC, int K, int OCpad, int KPAD) {
    int idx = blockIdx.x * 256 + threadIdx.x;
    if (idx >= OCpad * KPAD) return;
    int oc = idx / KPAD, k = idx - oc * KPAD;
    float v = (oc < OC && k < K) ? w[(size_t)oc * K + k] : 0.f;
    const int kc = k >> 5, r = k & 31;
    const int ks = r >> 4, lhi = (r >> 3) & 1, j = r & 7;
    const size_t dst = (size_t)kc * 32 * OCpad + ks * 16 * OCpad + oc * 16 + lhi * 8 + j;
    whiF[dst] = f16_rn(v);
}

// ---------------------------------------------------------------------------
// Deform weight prep -> fragment-ready fp16 (k-major kidx = k9*64 + c).
// ---------------------------------------------------------------------------
__global__ __launch_bounds__(256) void prep_wdf_k(const float* __restrict__ w,
                                                  ushort* __restrict__ whiF) {
    int idx = blockIdx.x * 256 + threadIdx.x;
    if (idx >= 64 * 576) return;
    int oc = idx / 576, rem = idx - oc * 576;
    int k9 = rem / 64, c = rem & 63;
    float v = w[(size_t)oc * 576 + c * 9 + k9];
    const int hv = c >> 5, r = c & 31;
    const int ks = r >> 4, lhi = (r >> 3) & 1, j = r & 7;
    const size_t dst = (size_t)((k9 * 2 + hv) * 2 + ks) * 1024 + oc * 16 + lhi * 8 + j;
    whiF[dst] = f16_rn(v);
}

// ---------------------------------------------------------------------------
// Input concat -> fp16 planes [b][132][H][W] (ch 130,131 zero).
// ---------------------------------------------------------------------------
__global__ __launch_bounds__(256) void cvt_in_k(const float* __restrict__ xfw,
                                                const float* __restrict__ xcur,
                                                const float* __restrict__ flow,
                                                ushort* __restrict__ concatP) {
    int idx = blockIdx.x * 256 + threadIdx.x;
    if (idx >= BB * 132 * HWSZ) return;
    int b = idx / (132 * HWSZ);
    int rem = idx - b * 132 * HWSZ;
    int c = rem / HWSZ, pix = rem - c * HWSZ;
    float v = 0.f;
    if (c < 64)       v = xfw [((size_t)b * 64 + c)       * HWSZ + pix];
    else if (c < 128) v = xcur[((size_t)b * 64 + c - 64)  * HWSZ + pix];
    else if (c < 130) v = flow[((size_t)b * 2  + c - 128) * HWSZ + pix];
    concatP[idx] = f16_rn(v);
}

// ---------------------------------------------------------------------------
// Pack x into gather-friendly float4: xP[b][dg][pix]
// ---------------------------------------------------------------------------
__global__ __launch_bounds__(256) void pack_x_k(const float* __restrict__ x,
                                                float4* __restrict__ xP) {
    int idx = blockIdx.x * 256 + threadIdx.x;
    if (idx >= BB * 16 * HWSZ) return;
    int b = idx / (16 * HWSZ);
    int rem = idx - b * 16 * HWSZ;
    int dg = rem / HWSZ, pix = rem - dg * HWSZ;
    const float* src = x + ((size_t)b * 64 + dg * 4) * HWSZ + pix;
    float4 v;
    v.x = src[0];
    v.y = src[HWSZ];
    v.z = src[2 * HWSZ];
    v.w = src[3 * HWSZ];
    xP[idx] = v;
}

// ---------------------------------------------------------------------------
// conv0/1/2: single-fp16 implicit-GEMM, 2-ROW tile (64 oc x 256 px).
// 512 threads = 8 waves (2M x 4N); each wave 32oc x 64px (2 pg).
// ---------------------------------------------------------------------------
template<int IC, int KPAD>
__global__ __launch_bounds__(512, 4) void conv_n256(
    const ushort* __restrict__ inP, const ushort* __restrict__ whiF,
    const float* __restrict__ bias, ushort* __restrict__ outP)
{
    constexpr int NCHUNK = KPAD / 32;
    constexpr int LDK = 40;
    constexpr int NBLK = BB * 64;      // 256 blocks (2 rows each)
    constexpr int PER = NBLK / 8;

    __shared__ ushort iB[2][256 * LDK];   // 40 KB

    const int tid = threadIdx.x;
    const int id  = blockIdx.x;
    const int orig = (id & 7) * PER + (id >> 3);   // XCD-chunked bijective
    const int b   = orig >> 6;
    const int y0r = (orig & 63) * 2;

    const int wave = tid >> 6, lane = tid & 63;
    const int wm = wave >> 2, wn = wave & 3;
    const int l31 = lane & 31, lhi = lane >> 5;

    const int px2 = tid & 255;                     // staging slot (row*128+px)
    const int spx = px2 & 127;
    const int srow = __builtin_amdgcn_readfirstlane((tid >> 7) & 1);
    const int skh  = __builtin_amdgcn_readfirstlane(tid >> 8);   // 16-k half

    f32x16 acc[2] = {};
    ushort pb[16];

    auto FETCH = [&](int kc) {
        #pragma unroll
        for (int j = 0; j < 16; ++j) {
            const int k  = kc * 32 + skh * 16 + j;   // wave-uniform
            const int ic = k / 9;
            const int kk = k - ic * 9;
            const int ky = kk / 3;
            const int kx = kk - ky * 3;
            const int gyy = y0r + srow + ky - 1;     // wave-uniform
            const int gx = spx + kx - 1;             // per-lane
            ushort u = 0;
            if ((unsigned)gyy < (unsigned)HH && (unsigned)gx < (unsigned)WW)
                u = inP[((size_t)b * IC + ic) * HWSZ + gyy * WW + gx];
            pb[j] = u;
        }
    };
    auto WRITE = [&](int buf) {
        short8 w0v, w1v;
        #pragma unroll
        for (int j = 0; j < 8; ++j) { w0v[j] = (short)pb[j]; w1v[j] = (short)pb[8 + j]; }
        *(short8*)&iB[buf][px2 * LDK + skh * 16]     = w0v;
        *(short8*)&iB[buf][px2 * LDK + skh * 16 + 8] = w1v;
    };

    FETCH(0);
    WRITE(0);

    for (int kc = 0; kc < NCHUNK; ++kc) {
        __syncthreads();
        const int cur = kc & 1;

        half8 af[2];
        #pragma unroll
        for (int ks = 0; ks < 2; ++ks) {
            const size_t ga = (size_t)kc * 32 * 64 + (size_t)ks * 16 * 64
                            + (wm * 32 + l31) * 16 + lhi * 8;
            af[ks] = __builtin_bit_cast(half8, *(const short8*)&whiF[ga]);
        }
        if (kc + 1 < NCHUNK) FETCH(kc + 1);

        #pragma unroll
        for (int ks = 0; ks < 2; ++ks) {
            const int koff = ks * 16 + lhi * 8;
            #pragma unroll
            for (int pg = 0; pg < 2; ++pg) {
                const int ib = (pg * 128 + wn * 32 + l31) * LDK + koff;
                const half8 bh = __builtin_bit_cast(half8, *(const short8*)&iB[cur][ib]);
                acc[pg] = __builtin_amdgcn_mfma_f32_32x32x16_f16(af[ks], bh, acc[pg], 0, 0, 0);
            }
        }

        if (kc + 1 < NCHUNK) WRITE(1 - cur);
    }

    const int px = wn * 32 + l31;
    #pragma unroll
    for (int pg = 0; pg < 2; ++pg) {
        const int y = y0r + pg;
        #pragma unroll
        for (int r = 0; r < 16; ++r) {
            const int oc = wm * 32 + (r & 3) + 8 * (r >> 2) + 4 * lhi;
            float v = acc[pg][r] + bias[oc];
            v = v >= 0.f ? v : 0.1f * v;
            outP[((size_t)b * 64 + oc) * HWSZ + y * WW + px] = f16_rn(v);
        }
    }
}

// ---------------------------------------------------------------------------
// conv3: single-fp16, M-tile 256 (NG=4) x 128 px, NGY=2, 512 threads.
// ---------------------------------------------------------------------------
template<int KPAD>
__global__ __launch_bounds__(512, 4) void conv_m512(
    const ushort* __restrict__ inP, const ushort* __restrict__ whiF,
    const float* __restrict__ bias, float* __restrict__ outF,
    const float* __restrict__ flow)
{
    constexpr int NCHUNK = KPAD / 32;
    constexpr int LDK = 40;
    constexpr int OCPAD = 512;
    constexpr int NBLK = BB * HH * 2;  // 1024
    constexpr int PER = NBLK / 8;

    __shared__ ushort iB[2][128 * LDK];   // 20 KB

    const int tid = threadIdx.x;
    const int id  = blockIdx.x;
    const int orig = (id & 7) * PER + (id >> 3);
    const int row = orig >> 1, gy = orig & 1;
    const int b = row >> 7, y = row & 127;
    const int o0 = gy * 256;

    const int wave = tid >> 6, lane = tid & 63;
    const int wm = wave >> 2, wn = wave & 3;
    const int l31 = lane & 31, lhi = lane >> 5;
    const int spx = tid & 127;
    const int sko = __builtin_amdgcn_readfirstlane(tid >> 7);

    f32x16 acc[4] = {};
    ushort pb[8];

    auto FETCH4 = [&](int kc, int j0) {
        #pragma unroll
        for (int j = j0; j < j0 + 4; ++j) {
            const int k  = kc * 32 + sko * 8 + j;
            const int ic = k / 9;
            const int kk = k - ic * 9;
            const int ky = kk / 3;
            const int kx = kk - ky * 3;
            const int gyy = y + ky - 1;
            const int gx = spx + kx - 1;
            ushort u = 0;
            if ((unsigned)gyy < (unsigned)HH && (unsigned)gx < (unsigned)WW)
                u = inP[((size_t)b * 64 + ic) * HWSZ + gyy * WW + gx];
            pb[j] = u;
        }
    };
    auto WRITE = [&](int buf) {
        short8 pw;
        #pragma unroll
        for (int j = 0; j < 8; ++j) pw[j] = (short)pb[j];
        *(short8*)&iB[buf][spx * LDK + sko * 8] = pw;
    };

    FETCH4(0, 0); FETCH4(0, 4);
    WRITE(0);

    for (int kc = 0; kc < NCHUNK; ++kc) {
        __syncthreads();
        const int cur = kc & 1;
        const bool more = (kc + 1 < NCHUNK);

        #pragma unroll
        for (int ks = 0; ks < 2; ++ks) {
            half8 af[4];
            #pragma unroll
            for (int mg = 0; mg < 4; ++mg) {
                const size_t ga = (size_t)kc * 32 * OCPAD + (size_t)ks * 16 * OCPAD
                                + (o0 + wm * 128 + mg * 32 + l31) * 16 + lhi * 8;
                af[mg] = __builtin_bit_cast(half8, *(const short8*)&whiF[ga]);
            }
            if (more) FETCH4(kc + 1, ks * 4);

            const int koff = ks * 16 + lhi * 8;
            const int ib = (wn * 32 + l31) * LDK + koff;
            const half8 bh = __builtin_bit_cast(half8, *(const short8*)&iB[cur][ib]);
            #pragma unroll
            for (int mg = 0; mg < 4; ++mg)
                acc[mg] = __builtin_amdgcn_mfma_f32_32x32x16_f16(af[mg], bh, acc[mg], 0, 0, 0);
        }

        if (more) WRITE(1 - cur);
    }

    const int px = wn * 32 + l31;
    #pragma unroll
    for (int mg = 0; mg < 4; ++mg) {
        #pragma unroll
        for (int r = 0; r < 16; ++r) {
            const int oc = o0 + wm * 128 + mg * 32 + (r & 3) + 8 * (r >> 2) + 4 * lhi;
            if (oc < 432) {
                float v = acc[mg][r] + bias[oc];
                float res;
                if (oc < 288) {
                    const float fl = flow[(((size_t)b * 2 + ((oc & 1) ? 0 : 1)) * HH + y) * WW + px];
                    res = 10.f * tanhf(v) + fl;
                } else {
                    res = 1.f / (1.f + expf(-v));
                }
                outF[((size_t)b * 432 + oc) * HWSZ + y * WW + px] = res;
            }
        }
    }
}

// ---------------------------------------------------------------------------
// MFMA deformable conv v9: 32 px/block, 2048 blocks (8 blocks/CU), 256
// threads = 4 waves, each wave one (k9-half x hv) quadrant of K.
// __launch_bounds__(256, 4): VGPR cap 128 -> no spill (round-10's (256,8)
// forced a 64-VGPR cap and spilled ~500MB of scratch). With ~60 VGPR the
// HW can still co-schedule 8 waves/SIMD from the 8 resident blocks.
// ---------------------------------------------------------------------------
__global__ __launch_bounds__(256, 4) void deform_v9(
    const float4* __restrict__ xP, const float* __restrict__ offm,
    const ushort* __restrict__ wdfh,
    const float* __restrict__ bias, float* __restrict__ outp)
{
    __shared__ float red[2][64][33];   // 16.9 KB

    const int tid = threadIdx.x;
    const int id  = blockIdx.x;
    const int orig = (id & 7) * 256 + (id >> 3);   // 2048 blocks, bijective
    const int x0 = (orig & 3) * 32;
    const int rl = orig >> 2;
    const int y = rl & 127, b = rl >> 7;

    const int wave = tid >> 6, lane = tid & 63;
    const int l31 = lane & 31, lhi = lane >> 5;
    const int k9h = wave >> 1;         // k9 half: 0 -> [0,5), 1 -> [5,9)
    const int hv  = wave & 1;          // dg half

    const int xp  = x0 + l31;          // this lane's pixel (B column)
    const int pix = y * WW + xp;
    const float* offb = offm + (size_t)b * 432 * HWSZ;
    const float fy = (float)y, fx = (float)xp;

    f32x16 acc[2] = {};

    const int k9lo = k9h ? 5 : 0;
    const int k9hi = k9h ? 9 : 5;
    for (int k9 = k9lo; k9 < k9hi; ++k9) {
        const float kyf = (float)(k9 / 3 - 1);
        const float kxf = (float)(k9 % 3 - 1);
        #pragma unroll
        for (int ks = 0; ks < 2; ++ks) {
            short8 bfs;
            #pragma unroll
            for (int d2 = 0; d2 < 2; ++d2) {
                const int dg = hv * 8 + ks * 4 + lhi * 2 + d2;
                const float dy = offb[(size_t)(dg * 18 + k9 * 2)     * HWSZ + pix];
                const float dx = offb[(size_t)(dg * 18 + k9 * 2 + 1) * HWSZ + pix];
                const float mk = offb[(size_t)(288 + dg * 9 + k9)    * HWSZ + pix];
                const float py = dy + kyf + fy;
                const float px = dx + kxf + fx;
                const float y0f = floorf(py), x0f = floorf(px);
                const float ly = py - y0f, lx = px - x0f;
                const int yi = (int)y0f, xi = (int)x0f;
                const float w00 = (1.f - ly) * (1.f - lx), w01 = (1.f - ly) * lx;
                const float w10 = ly * (1.f - lx),         w11 = ly * lx;
                const bool vy0 = (unsigned)yi < (unsigned)HH, vy1 = (unsigned)(yi + 1) < (unsigned)HH;
                const bool vx0 = (unsigned)xi < (unsigned)WW, vx1 = (unsigned)(xi + 1) < (unsigned)WW;
                const float f00 = (vy0 && vx0) ? w00 * mk : 0.f;
                const float f01 = (vy0 && vx1) ? w01 * mk : 0.f;
                const float f10 = (vy1 && vx0) ? w10 * mk : 0.f;
                const float f11 = (vy1 && vx1) ? w11 * mk : 0.f;
                const int cy0 = min(max(yi, 0), HH - 1), cy1 = min(max(yi + 1, 0), HH - 1);
                const int cx0 = min(max(xi, 0), WW - 1), cx1 = min(max(xi + 1, 0), WW - 1);
                const float4* xg = xP + (size_t)(b * 16 + dg) * HWSZ;
                const float4 c00 = xg[cy0 * WW + cx0], c01 = xg[cy0 * WW + cx1];
                const float4 c10 = xg[cy1 * WW + cx0], c11 = xg[cy1 * WW + cx1];
                bfs[d2 * 4 + 0] = (short)f16_rn(f00 * c00.x + f01 * c01.x + f10 * c10.x + f11 * c11.x);
                bfs[d2 * 4 + 1] = (short)f16_rn(f00 * c00.y + f01 * c01.y + f10 * c10.y + f11 * c11.y);
                bfs[d2 * 4 + 2] = (short)f16_rn(f00 * c00.z + f01 * c01.z + f10 * c10.z + f11 * c11.z);
                bfs[d2 * 4 + 3] = (short)f16_rn(f00 * c00.w + f01 * c01.w + f10 * c10.w + f11 * c11.w);
            }
            const half8 bf = __builtin_bit_cast(half8, bfs);
            const size_t abase = (size_t)((k9 * 2 + hv) * 2 + ks) * 1024 + l31 * 16 + lhi * 8;
            #pragma unroll
            for (int mg = 0; mg < 2; ++mg) {
                const half8 ah = __builtin_bit_cast(half8, *(const short8*)&wdfh[abase + mg * 512]);
                acc[mg] = __builtin_amdgcn_mfma_f32_32x32x16_f16(ah, bf, acc[mg], 0, 0, 0);
            }
        }
    }

    // ---- two-phase cross-wave reduction: (0+2),(1+3) then 0+1 ----
    if (wave >= 2) {
        #pragma unroll
        for (int mg = 0; mg < 2; ++mg)
            #pragma unroll
            for (int r = 0; r < 16; ++r)
                red[wave - 2][lane][mg * 16 + r] = acc[mg][r];
    }
    __syncthreads();
    if (wave < 2) {
        #pragma unroll
        for (int mg = 0; mg < 2; ++mg)
            #pragma unroll
            for (int r = 0; r < 16; ++r)
                acc[mg][r] += red[wave][lane][mg * 16 + r];
    }
    __syncthreads();
    if (wave == 1) {
        #pragma unroll
        for (int mg = 0; mg < 2; ++mg)
            #pragma unroll
            for (int r = 0; r < 16; ++r)
                red[0][lane][mg * 16 + r] = acc[mg][r];
    }
    __syncthreads();
    if (wave == 0) {
        #pragma unroll
        for (int mg = 0; mg < 2; ++mg)
            #pragma unroll
            for (int r = 0; r < 16; ++r) {
                const int oc = mg * 32 + (r & 3) + 8 * (r >> 2) + 4 * lhi;
                const float v = acc[mg][r] + red[0][lane][mg * 16 + r] + bias[oc];
                outp[(((size_t)b * 64 + oc) * HH + y) * WW + xp] = v;
            }
    }
}

// ---------------------------------------------------------------------------
extern "C" void kernel_launch(void* const* d_in, const int* in_sizes, int n_in,
                              void* d_out, int out_size, void* d_ws, size_t ws_size,
                              hipStream_t stream) {
    const float* x    = (const float*)d_in[0];
    const float* xfw  = (const float*)d_in[1];
    const float* xcur = (const float*)d_in[2];
    const float* flow = (const float*)d_in[3];
    const float* w0   = (const float*)d_in[4];
    const float* b0   = (const float*)d_in[5];
    const float* w1   = (const float*)d_in[6];
    const float* b1   = (const float*)d_in[7];
    const float* w2   = (const float*)d_in[8];
    const float* b2   = (const float*)d_in[9];
    const float* w3   = (const float*)d_in[10];
    const float* b3   = (const float*)d_in[11];
    const float* wdcn = (const float*)d_in[12];
    const float* bdcn = (const float*)d_in[13];
    float* out = (float*)d_out;

    // workspace (aliased; stream order makes it safe):
    //   [0, 113.2MB) offm fp32 (concatP fp16 17.3MB aliases head, dead before conv3)
    //   h0P fp16 8.4MB (conv2 reuses = h2P) | h1P fp16 8.4MB |
    //   xP float4 16.8MB | single-plane fp16 weights ~1MB
    float* offm     = (float*)d_ws;
    ushort* concatP = (ushort*)d_ws;
    ushort* h0P     = (ushort*)((char*)d_ws + (size_t)BB * 432 * HWSZ * 4);
    ushort* h1P     = h0P + (size_t)BB * 64 * HWSZ;
    float4* xP      = (float4*)(h1P + (size_t)BB * 64 * HWSZ);
    ushort* wp      = (ushort*)(xP + (size_t)BB * 16 * HWSZ);
    ushort* wdh = wp;
    ushort* w0h = wdh + 64 * 576;
    ushort* w1h = w0h + 64 * 1184;
    ushort* w2h = w1h + 64 * 576;
    ushort* w3h = w2h + 64 * 576;          // 512*576
    ushort* h2P = h0P;                     // conv2 output reuses h0P

    prep_wf_k<<<dim3((64 * 1184 + 255) / 256), dim3(256), 0, stream>>>(w0, w0h, 64, 1170, 64, 1184);
    prep_wf_k<<<dim3((64 * 576 + 255) / 256),  dim3(256), 0, stream>>>(w1, w1h, 64, 576, 64, 576);
    prep_wf_k<<<dim3((64 * 576 + 255) / 256),  dim3(256), 0, stream>>>(w2, w2h, 64, 576, 64, 576);
    prep_wf_k<<<dim3((512 * 576 + 255) / 256), dim3(256), 0, stream>>>(w3, w3h, 432, 576, 512, 576);
    prep_wdf_k<<<dim3((64 * 576 + 255) / 256), dim3(256), 0, stream>>>(wdcn, wdh);
    cvt_in_k<<<dim3((BB * 132 * HWSZ + 255) / 256), dim3(256), 0, stream>>>(xfw, xcur, flow, concatP);

    conv_n256<132, 1184><<<dim3(BB * 64), dim3(512), 0, stream>>>(concatP, w0h, b0, h0P);
    conv_n256<64, 576><<<dim3(BB * 64), dim3(512), 0, stream>>>(h0P, w1h, b1, h1P);
    conv_n256<64, 576><<<dim3(BB * 64), dim3(512), 0, stream>>>(h1P, w2h, b2, h2P);
    pack_x_k<<<dim3((BB * 16 * HWSZ + 255) / 256), dim3(256), 0, stream>>>(x, xP);
    conv_m512<576><<<dim3(BB * HH * 2), dim3(512), 0, stream>>>(h2P, w3h, b3, offm, flow);

    deform_v9<<<dim3(2048), dim3(256), 0, stream>>>(xP, offm, wdh, bdcn, out);
}

// Round 12
// 355.973 us; speedup vs baseline: 1.5635x; 1.1084x over previous
//
#include <hip/hip_runtime.h>
#include <hip/hip_bf16.h>
#include <cmath>

#define HH 128
#define WW 128
#define HWSZ (HH*WW)
#define BB 4

typedef __attribute__((ext_vector_type(8))) short short8;
typedef __attribute__((ext_vector_type(4))) short sh4;
typedef _Float16 half8 __attribute__((ext_vector_type(8)));
typedef __attribute__((ext_vector_type(16))) float f32x16;

__device__ __forceinline__ ushort f16_rn(float f) {
    _Float16 h = (_Float16)f;
    return __builtin_bit_cast(ushort, h);
}
__device__ __forceinline__ float f16_f(ushort u) {
    return (float)__builtin_bit_cast(_Float16, u);
}

// ---------------------------------------------------------------------------
// Weight prep -> FRAGMENT-READY fp16 (single plane):
//   dst = kc*32*OCpad + ks*16*OCpad + oc*16 + lhi*8 + j
// ---------------------------------------------------------------------------
__global__ __launch_bounds__(256) void prep_wf_k(const float* __restrict__ w,
                                                 ushort* __restrict__ whiF,
                                                 int OC, int K, int OCpad, int KPAD) {
    int idx = blockIdx.x * 256 + threadIdx.x;
    if (idx >= OCpad * KPAD) return;
    int oc = idx / KPAD, k = idx - oc * KPAD;
    float v = (oc < OC && k < K) ? w[(size_t)oc * K + k] : 0.f;
    const int kc = k >> 5, r = k & 31;
    const int ks = r >> 4, lhi = (r >> 3) & 1, j = r & 7;
    const size_t dst = (size_t)kc * 32 * OCpad + ks * 16 * OCpad + oc * 16 + lhi * 8 + j;
    whiF[dst] = f16_rn(v);
}

// ---------------------------------------------------------------------------
// Deform weight prep -> fragment-ready fp16 (k-major kidx = k9*64 + c).
// ---------------------------------------------------------------------------
__global__ __launch_bounds__(256) void prep_wdf_k(const float* __restrict__ w,
                                                  ushort* __restrict__ whiF) {
    int idx = blockIdx.x * 256 + threadIdx.x;
    if (idx >= 64 * 576) return;
    int oc = idx / 576, rem = idx - oc * 576;
    int k9 = rem / 64, c = rem & 63;
    float v = w[(size_t)oc * 576 + c * 9 + k9];
    const int hv = c >> 5, r = c & 31;
    const int ks = r >> 4, lhi = (r >> 3) & 1, j = r & 7;
    const size_t dst = (size_t)((k9 * 2 + hv) * 2 + ks) * 1024 + oc * 16 + lhi * 8 + j;
    whiF[dst] = f16_rn(v);
}

// ---------------------------------------------------------------------------
// Input concat -> fp16 planes [b][132][H][W] (ch 130,131 zero).
// ---------------------------------------------------------------------------
__global__ __launch_bounds__(256) void cvt_in_k(const float* __restrict__ xfw,
                                                const float* __restrict__ xcur,
                                                const float* __restrict__ flow,
                                                ushort* __restrict__ concatP) {
    int idx = blockIdx.x * 256 + threadIdx.x;
    if (idx >= BB * 132 * HWSZ) return;
    int b = idx / (132 * HWSZ);
    int rem = idx - b * 132 * HWSZ;
    int c = rem / HWSZ, pix = rem - c * HWSZ;
    float v = 0.f;
    if (c < 64)       v = xfw [((size_t)b * 64 + c)       * HWSZ + pix];
    else if (c < 128) v = xcur[((size_t)b * 64 + c - 64)  * HWSZ + pix];
    else if (c < 130) v = flow[((size_t)b * 2  + c - 128) * HWSZ + pix];
    concatP[idx] = f16_rn(v);
}

// ---------------------------------------------------------------------------
// Pack x into gather-friendly fp16x4: xP[b][dg][pix] (8B per gather).
// ---------------------------------------------------------------------------
__global__ __launch_bounds__(256) void pack_x_k(const float* __restrict__ x,
                                                sh4* __restrict__ xP) {
    int idx = blockIdx.x * 256 + threadIdx.x;
    if (idx >= BB * 16 * HWSZ) return;
    int b = idx / (16 * HWSZ);
    int rem = idx - b * 16 * HWSZ;
    int dg = rem / HWSZ, pix = rem - dg * HWSZ;
    const float* src = x + ((size_t)b * 64 + dg * 4) * HWSZ + pix;
    sh4 v;
    v[0] = (short)f16_rn(src[0]);
    v[1] = (short)f16_rn(src[HWSZ]);
    v[2] = (short)f16_rn(src[2 * HWSZ]);
    v[3] = (short)f16_rn(src[3 * HWSZ]);
    xP[idx] = v;
}

// ---------------------------------------------------------------------------
// conv0/1/2: single-fp16 implicit-GEMM, 2-ROW tile (64 oc x 256 px).
// 512 threads = 8 waves (2M x 4N); each wave 32oc x 64px (2 pg).
// ---------------------------------------------------------------------------
template<int IC, int KPAD>
__global__ __launch_bounds__(512, 4) void conv_n256(
    const ushort* __restrict__ inP, const ushort* __restrict__ whiF,
    const float* __restrict__ bias, ushort* __restrict__ outP)
{
    constexpr int NCHUNK = KPAD / 32;
    constexpr int LDK = 40;
    constexpr int NBLK = BB * 64;      // 256 blocks (2 rows each)
    constexpr int PER = NBLK / 8;

    __shared__ ushort iB[2][256 * LDK];   // 40 KB

    const int tid = threadIdx.x;
    const int id  = blockIdx.x;
    const int orig = (id & 7) * PER + (id >> 3);   // XCD-chunked bijective
    const int b   = orig >> 6;
    const int y0r = (orig & 63) * 2;

    const int wave = tid >> 6, lane = tid & 63;
    const int wm = wave >> 2, wn = wave & 3;
    const int l31 = lane & 31, lhi = lane >> 5;

    const int px2 = tid & 255;                     // staging slot (row*128+px)
    const int spx = px2 & 127;
    const int srow = __builtin_amdgcn_readfirstlane((tid >> 7) & 1);
    const int skh  = __builtin_amdgcn_readfirstlane(tid >> 8);   // 16-k half

    f32x16 acc[2] = {};
    ushort pb[16];

    auto FETCH = [&](int kc) {
        #pragma unroll
        for (int j = 0; j < 16; ++j) {
            const int k  = kc * 32 + skh * 16 + j;   // wave-uniform
            const int ic = k / 9;
            const int kk = k - ic * 9;
            const int ky = kk / 3;
            const int kx = kk - ky * 3;
            const int gyy = y0r + srow + ky - 1;     // wave-uniform
            const int gx = spx + kx - 1;             // per-lane
            ushort u = 0;
            if ((unsigned)gyy < (unsigned)HH && (unsigned)gx < (unsigned)WW)
                u = inP[((size_t)b * IC + ic) * HWSZ + gyy * WW + gx];
            pb[j] = u;
        }
    };
    auto WRITE = [&](int buf) {
        short8 w0v, w1v;
        #pragma unroll
        for (int j = 0; j < 8; ++j) { w0v[j] = (short)pb[j]; w1v[j] = (short)pb[8 + j]; }
        *(short8*)&iB[buf][px2 * LDK + skh * 16]     = w0v;
        *(short8*)&iB[buf][px2 * LDK + skh * 16 + 8] = w1v;
    };

    FETCH(0);
    WRITE(0);

    for (int kc = 0; kc < NCHUNK; ++kc) {
        __syncthreads();
        const int cur = kc & 1;

        half8 af[2];
        #pragma unroll
        for (int ks = 0; ks < 2; ++ks) {
            const size_t ga = (size_t)kc * 32 * 64 + (size_t)ks * 16 * 64
                            + (wm * 32 + l31) * 16 + lhi * 8;
            af[ks] = __builtin_bit_cast(half8, *(const short8*)&whiF[ga]);
        }
        if (kc + 1 < NCHUNK) FETCH(kc + 1);

        #pragma unroll
        for (int ks = 0; ks < 2; ++ks) {
            const int koff = ks * 16 + lhi * 8;
            #pragma unroll
            for (int pg = 0; pg < 2; ++pg) {
                const int ib = (pg * 128 + wn * 32 + l31) * LDK + koff;
                const half8 bh = __builtin_bit_cast(half8, *(const short8*)&iB[cur][ib]);
                acc[pg] = __builtin_amdgcn_mfma_f32_32x32x16_f16(af[ks], bh, acc[pg], 0, 0, 0);
            }
        }

        if (kc + 1 < NCHUNK) WRITE(1 - cur);
    }

    const int px = wn * 32 + l31;
    #pragma unroll
    for (int pg = 0; pg < 2; ++pg) {
        const int y = y0r + pg;
        #pragma unroll
        for (int r = 0; r < 16; ++r) {
            const int oc = wm * 32 + (r & 3) + 8 * (r >> 2) + 4 * lhi;
            float v = acc[pg][r] + bias[oc];
            v = v >= 0.f ? v : 0.1f * v;
            outP[((size_t)b * 64 + oc) * HWSZ + y * WW + px] = f16_rn(v);
        }
    }
}

// ---------------------------------------------------------------------------
// conv3: single-fp16, M-tile 256 (NG=4) x 128 px, NGY=2, 512 threads.
// Epilogue writes PACKED fp16 offsets: offP[b][m=dg*9+k9][pix] = dy|dx<<16
// (the even/odd oc pair sits in this thread's consecutive r's), and fp16
// masks mskP[b][m][pix]. Halves offm HBM write vs fp32.
// ---------------------------------------------------------------------------
template<int KPAD>
__global__ __launch_bounds__(512, 4) void conv_m512(
    const ushort* __restrict__ inP, const ushort* __restrict__ whiF,
    const float* __restrict__ bias, uint* __restrict__ offP,
    ushort* __restrict__ mskP, const float* __restrict__ flow)
{
    constexpr int NCHUNK = KPAD / 32;
    constexpr int LDK = 40;
    constexpr int OCPAD = 512;
    constexpr int NBLK = BB * HH * 2;  // 1024
    constexpr int PER = NBLK / 8;

    __shared__ ushort iB[2][128 * LDK];   // 20 KB

    const int tid = threadIdx.x;
    const int id  = blockIdx.x;
    const int orig = (id & 7) * PER + (id >> 3);
    const int row = orig >> 1, gy = orig & 1;
    const int b = row >> 7, y = row & 127;
    const int o0 = gy * 256;

    const int wave = tid >> 6, lane = tid & 63;
    const int wm = wave >> 2, wn = wave & 3;
    const int l31 = lane & 31, lhi = lane >> 5;
    const int spx = tid & 127;
    const int sko = __builtin_amdgcn_readfirstlane(tid >> 7);

    f32x16 acc[4] = {};
    ushort pb[8];

    auto FETCH4 = [&](int kc, int j0) {
        #pragma unroll
        for (int j = j0; j < j0 + 4; ++j) {
            const int k  = kc * 32 + sko * 8 + j;
            const int ic = k / 9;
            const int kk = k - ic * 9;
            const int ky = kk / 3;
            const int kx = kk - ky * 3;
            const int gyy = y + ky - 1;
            const int gx = spx + kx - 1;
            ushort u = 0;
            if ((unsigned)gyy < (unsigned)HH && (unsigned)gx < (unsigned)WW)
                u = inP[((size_t)b * 64 + ic) * HWSZ + gyy * WW + gx];
            pb[j] = u;
        }
    };
    auto WRITE = [&](int buf) {
        short8 pw;
        #pragma unroll
        for (int j = 0; j < 8; ++j) pw[j] = (short)pb[j];
        *(short8*)&iB[buf][spx * LDK + sko * 8] = pw;
    };

    FETCH4(0, 0); FETCH4(0, 4);
    WRITE(0);

    for (int kc = 0; kc < NCHUNK; ++kc) {
        __syncthreads();
        const int cur = kc & 1;
        const bool more = (kc + 1 < NCHUNK);

        #pragma unroll
        for (int ks = 0; ks < 2; ++ks) {
            half8 af[4];
            #pragma unroll
            for (int mg = 0; mg < 4; ++mg) {
                const size_t ga = (size_t)kc * 32 * OCPAD + (size_t)ks * 16 * OCPAD
                                + (o0 + wm * 128 + mg * 32 + l31) * 16 + lhi * 8;
                af[mg] = __builtin_bit_cast(half8, *(const short8*)&whiF[ga]);
            }
            if (more) FETCH4(kc + 1, ks * 4);

            const int koff = ks * 16 + lhi * 8;
            const int ib = (wn * 32 + l31) * LDK + koff;
            const half8 bh = __builtin_bit_cast(half8, *(const short8*)&iB[cur][ib]);
            #pragma unroll
            for (int mg = 0; mg < 4; ++mg)
                acc[mg] = __builtin_amdgcn_mfma_f32_32x32x16_f16(af[mg], bh, acc[mg], 0, 0, 0);
        }

        if (more) WRITE(1 - cur);
    }

    // ---- epilogue (packed fp16) ----
    const int px = wn * 32 + l31;
    const size_t pixb = (size_t)y * WW + px;
    const float fl0 = flow[((size_t)b * 2)     * HWSZ + pixb];
    const float fl1 = flow[((size_t)b * 2 + 1) * HWSZ + pixb];
    uint*   offb = offP + (size_t)b * 144 * HWSZ;
    ushort* mskb = mskP + (size_t)b * 144 * HWSZ;
    #pragma unroll
    for (int mg = 0; mg < 4; ++mg) {
        #pragma unroll
        for (int t = 0; t < 8; ++t) {
            const int r0 = 2 * t;
            const int oc = o0 + wm * 128 + mg * 32 + (r0 & 3) + 8 * (r0 >> 2) + 4 * lhi;
            const float vy = acc[mg][r0]     + bias[oc < 432 ? oc : 0];
            const float vx = acc[mg][r0 + 1] + bias[oc < 431 ? oc + 1 : 0];
            if (oc < 288) {
                const float ry = 10.f * tanhf(vy) + fl1;   // dy (even oc) adds flow ch1
                const float rx = 10.f * tanhf(vx) + fl0;   // dx (odd oc) adds flow ch0
                offb[(size_t)(oc >> 1) * HWSZ + pixb] =
                    (uint)f16_rn(ry) | ((uint)f16_rn(rx) << 16);
            } else if (oc < 432) {
                mskb[(size_t)(oc - 288) * HWSZ + pixb] = f16_rn(1.f / (1.f + expf(-vy)));
                mskb[(size_t)(oc - 287) * HWSZ + pixb] = f16_rn(1.f / (1.f + expf(-vx)));
            }
        }
    }
}

// ---------------------------------------------------------------------------
// MFMA deformable conv v10: fp16 packed inputs. 32 px/block, 2048 blocks,
// 256 threads = 4 waves (k9-half x hv quadrants), two-phase LDS reduction.
// Per sample: ONE uint load (dy|dx fp16) + one ushort (mask) + 4x 8B gathers.
// ---------------------------------------------------------------------------
__global__ __launch_bounds__(256, 4) void deform_v10(
    const sh4* __restrict__ xP, const uint* __restrict__ offP,
    const ushort* __restrict__ mskP, const ushort* __restrict__ wdfh,
    const float* __restrict__ bias, float* __restrict__ outp)
{
    __shared__ float red[2][64][33];   // 16.9 KB

    const int tid = threadIdx.x;
    const int id  = blockIdx.x;
    const int orig = (id & 7) * 256 + (id >> 3);   // 2048 blocks, bijective
    const int x0 = (orig & 3) * 32;
    const int rl = orig >> 2;
    const int y = rl & 127, b = rl >> 7;

    const int wave = tid >> 6, lane = tid & 63;
    const int l31 = lane & 31, lhi = lane >> 5;
    const int k9h = wave >> 1;         // k9 half: 0 -> [0,5), 1 -> [5,9)
    const int hv  = wave & 1;          // dg half

    const int xp  = x0 + l31;          // this lane's pixel (B column)
    const int pix = y * WW + xp;
    const uint*   offb = offP + (size_t)b * 144 * HWSZ;
    const ushort* mskb = mskP + (size_t)b * 144 * HWSZ;
    const float fy = (float)y, fx = (float)xp;

    f32x16 acc[2] = {};

    const int k9lo = k9h ? 5 : 0;
    const int k9hi = k9h ? 9 : 5;
    for (int k9 = k9lo; k9 < k9hi; ++k9) {
        const float kyf = (float)(k9 / 3 - 1);
        const float kxf = (float)(k9 % 3 - 1);
        #pragma unroll
        for (int ks = 0; ks < 2; ++ks) {
            short8 bfs;
            #pragma unroll
            for (int d2 = 0; d2 < 2; ++d2) {
                const int dg = hv * 8 + ks * 4 + lhi * 2 + d2;
                const int m  = dg * 9 + k9;
                const uint u = offb[(size_t)m * HWSZ + pix];
                const float dy = f16_f((ushort)(u & 0xffffu));
                const float dx = f16_f((ushort)(u >> 16));
                const float mk = f16_f(mskb[(size_t)m * HWSZ + pix]);
                const float py = dy + kyf + fy;
                const float px = dx + kxf + fx;
                const float y0f = floorf(py), x0f = floorf(px);
                const float ly = py - y0f, lx = px - x0f;
                const int yi = (int)y0f, xi = (int)x0f;
                const float w00 = (1.f - ly) * (1.f - lx), w01 = (1.f - ly) * lx;
                const float w10 = ly * (1.f - lx),         w11 = ly * lx;
                const bool vy0 = (unsigned)yi < (unsigned)HH, vy1 = (unsigned)(yi + 1) < (unsigned)HH;
                const bool vx0 = (unsigned)xi < (unsigned)WW, vx1 = (unsigned)(xi + 1) < (unsigned)WW;
                const float f00 = (vy0 && vx0) ? w00 * mk : 0.f;
                const float f01 = (vy0 && vx1) ? w01 * mk : 0.f;
                const float f10 = (vy1 && vx0) ? w10 * mk : 0.f;
                const float f11 = (vy1 && vx1) ? w11 * mk : 0.f;
                const int cy0 = min(max(yi, 0), HH - 1), cy1 = min(max(yi + 1, 0), HH - 1);
                const int cx0 = min(max(xi, 0), WW - 1), cx1 = min(max(xi + 1, 0), WW - 1);
                const sh4* xg = xP + (size_t)(b * 16 + dg) * HWSZ;
                const sh4 c00 = xg[cy0 * WW + cx0], c01 = xg[cy0 * WW + cx1];
                const sh4 c10 = xg[cy1 * WW + cx0], c11 = xg[cy1 * WW + cx1];
                #pragma unroll
                for (int n = 0; n < 4; ++n) {
                    const float s = f00 * f16_f((ushort)c00[n]) + f01 * f16_f((ushort)c01[n])
                                  + f10 * f16_f((ushort)c10[n]) + f11 * f16_f((ushort)c11[n]);
                    bfs[d2 * 4 + n] = (short)f16_rn(s);
                }
            }
            const half8 bf = __builtin_bit_cast(half8, bfs);
            const size_t abase = (size_t)((k9 * 2 + hv) * 2 + ks) * 1024 + l31 * 16 + lhi * 8;
            #pragma unroll
            for (int mg = 0; mg < 2; ++mg) {
                const half8 ah = __builtin_bit_cast(half8, *(const short8*)&wdfh[abase + mg * 512]);
                acc[mg] = __builtin_amdgcn_mfma_f32_32x32x16_f16(ah, bf, acc[mg], 0, 0, 0);
            }
        }
    }

    // ---- two-phase cross-wave reduction: (0+2),(1+3) then 0+1 ----
    if (wave >= 2) {
        #pragma unroll
        for (int mg = 0; mg < 2; ++mg)
            #pragma unroll
            for (int r = 0; r < 16; ++r)
                red[wave - 2][lane][mg * 16 + r] = acc[mg][r];
    }
    __syncthreads();
    if (wave < 2) {
        #pragma unroll
        for (int mg = 0; mg < 2; ++mg)
            #pragma unroll
            for (int r = 0; r < 16; ++r)
                acc[mg][r] += red[wave][lane][mg * 16 + r];
    }
    __syncthreads();
    if (wave == 1) {
        #pragma unroll
        for (int mg = 0; mg < 2; ++mg)
            #pragma unroll
            for (int r = 0; r < 16; ++r)
                red[0][lane][mg * 16 + r] = acc[mg][r];
    }
    __syncthreads();
    if (wave == 0) {
        #pragma unroll
        for (int mg = 0; mg < 2; ++mg)
            #pragma unroll
            for (int r = 0; r < 16; ++r) {
                const int oc = mg * 32 + (r & 3) + 8 * (r >> 2) + 4 * lhi;
                const float v = acc[mg][r] + red[0][lane][mg * 16 + r] + bias[oc];
                outp[(((size_t)b * 64 + oc) * HH + y) * WW + xp] = v;
            }
    }
}

// ---------------------------------------------------------------------------
extern "C" void kernel_launch(void* const* d_in, const int* in_sizes, int n_in,
                              void* d_out, int out_size, void* d_ws, size_t ws_size,
                              hipStream_t stream) {
    const float* x    = (const float*)d_in[0];
    const float* xfw  = (const float*)d_in[1];
    const float* xcur = (const float*)d_in[2];
    const float* flow = (const float*)d_in[3];
    const float* w0   = (const float*)d_in[4];
    const float* b0   = (const float*)d_in[5];
    const float* w1   = (const float*)d_in[6];
    const float* b1   = (const float*)d_in[7];
    const float* w2   = (const float*)d_in[8];
    const float* b2   = (const float*)d_in[9];
    const float* w3   = (const float*)d_in[10];
    const float* b3   = (const float*)d_in[11];
    const float* wdcn = (const float*)d_in[12];
    const float* bdcn = (const float*)d_in[13];
    float* out = (float*)d_out;

    // workspace (aliased; stream order makes it safe):
    //   offP uint [4][144][HWSZ] 37.7MB  (concatP fp16 17.3MB aliases head,
    //        dead before conv3 writes offP)
    //   mskP ushort [4][144][HWSZ] 18.9MB
    //   h0P fp16 8.4MB (conv2 reuses = h2P) | h1P fp16 8.4MB |
    //   xP fp16x4 8.4MB | single-plane fp16 weights ~1MB
    uint*   offP    = (uint*)d_ws;
    ushort* concatP = (ushort*)d_ws;
    ushort* mskP    = (ushort*)(offP + (size_t)BB * 144 * HWSZ);
    ushort* h0P     = mskP + (size_t)BB * 144 * HWSZ;
    ushort* h1P     = h0P + (size_t)BB * 64 * HWSZ;
    sh4*    xPh     = (sh4*)(h1P + (size_t)BB * 64 * HWSZ);
    ushort* wp      = (ushort*)(xPh + (size_t)BB * 16 * HWSZ);
    ushort* wdh = wp;
    ushort* w0h = wdh + 64 * 576;
    ushort* w1h = w0h + 64 * 1184;
    ushort* w2h = w1h + 64 * 576;
    ushort* w3h = w2h + 64 * 576;          // 512*576
    ushort* h2P = h0P;                     // conv2 output reuses h0P

    prep_wf_k<<<dim3((64 * 1184 + 255) / 256), dim3(256), 0, stream>>>(w0, w0h, 64, 1170, 64, 1184);
    prep_wf_k<<<dim3((64 * 576 + 255) / 256),  dim3(256), 0, stream>>>(w1, w1h, 64, 576, 64, 576);
    prep_wf_k<<<dim3((64 * 576 + 255) / 256),  dim3(256), 0, stream>>>(w2, w2h, 64, 576, 64, 576);
    prep_wf_k<<<dim3((512 * 576 + 255) / 256), dim3(256), 0, stream>>>(w3, w3h, 432, 576, 512, 576);
    prep_wdf_k<<<dim3((64 * 576 + 255) / 256), dim3(256), 0, stream>>>(wdcn, wdh);
    cvt_in_k<<<dim3((BB * 132 * HWSZ + 255) / 256), dim3(256), 0, stream>>>(xfw, xcur, flow, concatP);

    conv_n256<132, 1184><<<dim3(BB * 64), dim3(512), 0, stream>>>(concatP, w0h, b0, h0P);
    conv_n256<64, 576><<<dim3(BB * 64), dim3(512), 0, stream>>>(h0P, w1h, b1, h1P);
    conv_n256<64, 576><<<dim3(BB * 64), dim3(512), 0, stream>>>(h1P, w2h, b2, h2P);
    pack_x_k<<<dim3((BB * 16 * HWSZ + 255) / 256), dim3(256), 0, stream>>>(x, xPh);
    conv_m512<576><<<dim3(BB * HH * 2), dim3(512), 0, stream>>>(h2P, w3h, b3, offP, mskP, flow);

    deform_v10<<<dim3(2048), dim3(256), 0, stream>>>(xPh, offP, mskP, wdh, bdcn, out);
}

// Round 13
// 308.610 us; speedup vs baseline: 1.8034x; 1.1535x over previous
//
#include <hip/hip_runtime.h>
#include <hip/hip_bf16.h>
#include <cmath>

#define HH 128
#define WW 128
#define HWSZ (HH*WW)
#define BB 4
#define PH 130   // padded spatial dim

typedef __attribute__((ext_vector_type(8))) short short8;
typedef __attribute__((ext_vector_type(4))) short sh4;
typedef _Float16 half8 __attribute__((ext_vector_type(8)));
typedef __attribute__((ext_vector_type(16))) float f32x16;

__device__ __forceinline__ ushort f16_rn(float f) {
    _Float16 h = (_Float16)f;
    return __builtin_bit_cast(ushort, h);
}
__device__ __forceinline__ float f16_f(ushort u) {
    return (float)__builtin_bit_cast(_Float16, u);
}

// ---------------------------------------------------------------------------
// Weight prep (conv0/1/2) -> per-tap fragment-ready fp16:
//   dst[((tap*ICSTEPS+ks)*64 + oc)*16 + lhi*8 + j] = w[oc][ic= ks*16+lhi*8+j][tap]
// ---------------------------------------------------------------------------
__global__ __launch_bounds__(256) void prep_wcm(const float* __restrict__ w,
                                                ushort* __restrict__ wOut,
                                                int ICREAL, int ICPAD) {
    const int ICSTEPS = ICPAD >> 4;
    int idx = blockIdx.x * 256 + threadIdx.x;
    if (idx >= 9 * ICSTEPS * 64 * 16) return;
    int j = idx & 7, lhi = (idx >> 3) & 1, oc = (idx >> 4) & 63, tk = idx >> 10;
    int tap = tk / ICSTEPS, ks = tk - tap * ICSTEPS;
    int ic = ks * 16 + lhi * 8 + j;
    float v = (ic < ICREAL) ? w[(size_t)oc * ICREAL * 9 + ic * 9 + tap] : 0.f;
    wOut[idx] = f16_rn(v);
}

// ---------------------------------------------------------------------------
// Weight prep (conv3, OCPAD=512) -> per-tap fragment-ready fp16.
// ---------------------------------------------------------------------------
__global__ __launch_bounds__(256) void prep_w3cm(const float* __restrict__ w,
                                                 ushort* __restrict__ wOut) {
    int idx = blockIdx.x * 256 + threadIdx.x;
    if (idx >= 36 * 512 * 16) return;
    int j = idx & 7, lhi = (idx >> 3) & 1, oc = (idx >> 4) & 511, tk = idx >> 13;
    int tap = tk >> 2, ks = tk & 3;
    int ic = ks * 16 + lhi * 8 + j;
    float v = (oc < 432) ? w[(size_t)oc * 576 + ic * 9 + tap] : 0.f;
    wOut[idx] = f16_rn(v);
}

// ---------------------------------------------------------------------------
// Deform weight prep -> fragment-ready fp16 (k-major kidx = k9*64 + c).
// ---------------------------------------------------------------------------
__global__ __launch_bounds__(256) void prep_wdf_k(const float* __restrict__ w,
                                                  ushort* __restrict__ whiF) {
    int idx = blockIdx.x * 256 + threadIdx.x;
    if (idx >= 64 * 576) return;
    int oc = idx / 576, rem = idx - oc * 576;
    int k9 = rem / 64, c = rem & 63;
    float v = w[(size_t)oc * 576 + c * 9 + k9];
    const int hv = c >> 5, r = c & 31;
    const int ks = r >> 4, lhi = (r >> 3) & 1, j = r & 7;
    const size_t dst = (size_t)((k9 * 2 + hv) * 2 + ks) * 1024 + oc * 16 + lhi * 8 + j;
    whiF[dst] = f16_rn(v);
}

// ---------------------------------------------------------------------------
// Concat {xfw,xcur,flow} -> channel-minor padded fp16 [b][130][130][144]
// (interior at [y+1][x+1]; c in [130,144) zero). LDS-tiled 32x32 transpose.
// ---------------------------------------------------------------------------
__global__ __launch_bounds__(256) void cvt_cm(const float* __restrict__ xfw,
                                              const float* __restrict__ xcur,
                                              const float* __restrict__ flow,
                                              ushort* __restrict__ out) {
    __shared__ ushort T[32][36];
    const int tid = threadIdx.x;
    const int b = blockIdx.x >> 7, y = blockIdx.x & 127;

    for (int c0 = 0; c0 < 144; c0 += 32) {
        for (int x0 = 0; x0 < 128; x0 += 32) {
            #pragma unroll
            for (int i = 0; i < 4; ++i) {
                const int cl = i * 8 + (tid >> 5);
                const int c = c0 + cl;
                const int x = x0 + (tid & 31);
                float v = 0.f;
                if (c < 64)       v = xfw [((size_t)b * 64 + c)       * HWSZ + y * WW + x];
                else if (c < 128) v = xcur[((size_t)b * 64 + c - 64)  * HWSZ + y * WW + x];
                else if (c < 130) v = flow[((size_t)b * 2  + c - 128) * HWSZ + y * WW + x];
                T[cl][tid & 31] = f16_rn(v);
            }
            __syncthreads();
            #pragma unroll
            for (int i = 0; i < 4; ++i) {
                const int xl = i * 8 + (tid >> 5);
                const int c = c0 + (tid & 31);
                if (c < 144)
                    out[(((size_t)b * PH + y + 1) * PH + x0 + xl + 1) * 144 + c] = T[tid & 31][xl];
            }
            __syncthreads();
        }
    }
}

// ---------------------------------------------------------------------------
// Pack x into gather-friendly fp16x4: xP[b][dg][pix].
// ---------------------------------------------------------------------------
__global__ __launch_bounds__(256) void pack_x_k(const float* __restrict__ x,
                                                sh4* __restrict__ xP) {
    int idx = blockIdx.x * 256 + threadIdx.x;
    if (idx >= BB * 16 * HWSZ) return;
    int b = idx / (16 * HWSZ);
    int rem = idx - b * 16 * HWSZ;
    int dg = rem / HWSZ, pix = rem - dg * HWSZ;
    const float* src = x + ((size_t)b * 64 + dg * 4) * HWSZ + pix;
    sh4 v;
    v[0] = (short)f16_rn(src[0]);
    v[1] = (short)f16_rn(src[HWSZ]);
    v[2] = (short)f16_rn(src[2 * HWSZ]);
    v[3] = (short)f16_rn(src[3 * HWSZ]);
    xP[idx] = v;
}

// ---------------------------------------------------------------------------
// Channel-minor conv3x3 (conv0/1/2): ZERO LDS, ZERO barriers.
// 512 thr = 8 waves (2 oc-half x 4 px-quarter); block = 64 oc x 128 px (1 row).
// Per tap/ks: A-frag = act (16B coalesced from padded channel-minor buffer),
// B-frag = per-tap fragment-ready weights. Operands SWAPPED (A=act, M=px;
// B=w, N=oc) so D is lane-owns-oc -> channel-minor stores are 64B-coalesced.
// ---------------------------------------------------------------------------
template<int ICPAD, int ICSTEPS>
__global__ __launch_bounds__(512, 4) void conv_cm(
    const ushort* __restrict__ actIn, const ushort* __restrict__ wT,
    const float* __restrict__ bias, ushort* __restrict__ actOut)
{
    constexpr int SYI = PH * ICPAD;
    const int tid = threadIdx.x;
    const int id  = blockIdx.x;
    const int orig = (id & 7) * 64 + (id >> 3);    // 512 blocks, XCD-chunked
    const int b = orig >> 7, y = orig & 127;

    const int wave = tid >> 6, lane = tid & 63;
    const int wm = wave >> 2, wn = wave & 3;
    const int l31 = lane & 31, lhi = lane >> 5;

    f32x16 acc = {};

    const ushort* arow = actIn + ((size_t)b * PH + y) * SYI
                       + (wn * 32 + l31) * ICPAD + lhi * 8;
    const ushort* wb = wT + (wm * 32 + l31) * 16 + lhi * 8;

    #pragma unroll
    for (int tap = 0; tap < 9; ++tap) {
        const int ky = tap / 3, kx = tap % 3;
        #pragma unroll
        for (int ks = 0; ks < ICSTEPS; ++ks) {
            const half8 af = __builtin_bit_cast(half8,
                *(const short8*)&arow[ky * SYI + kx * ICPAD + ks * 16]);
            const half8 wf = __builtin_bit_cast(half8,
                *(const short8*)&wb[(size_t)(tap * ICSTEPS + ks) * 1024]);
            acc = __builtin_amdgcn_mfma_f32_32x32x16_f16(af, wf, acc, 0, 0, 0);
        }
    }

    // epilogue: lane owns oc; D rows = px
    const int oc = wm * 32 + l31;
    const float bi = bias[oc];
    ushort* ob = actOut + (((size_t)b * PH + y + 1) * PH + 1) * 64 + oc;
    #pragma unroll
    for (int r = 0; r < 16; ++r) {
        const int px = wn * 32 + (r & 3) + 8 * (r >> 2) + 4 * lhi;
        float v = acc[r] + bi;
        v = v >= 0.f ? v : 0.1f * v;
        ob[(size_t)px * 64] = f16_rn(v);
    }
}

// ---------------------------------------------------------------------------
// conv3 channel-minor: ZERO LDS / barriers. M-tile 256 (NG=4) x 128 px,
// NGY=2. Old operand order (A=w, B=act) -> lane owns px for the pixel-major
// packed offP/mskP epilogue (identical to proven round-12 version).
// ---------------------------------------------------------------------------
__global__ __launch_bounds__(512, 4) void conv3_cm(
    const ushort* __restrict__ actIn, const ushort* __restrict__ wT3,
    const float* __restrict__ bias, uint* __restrict__ offP,
    ushort* __restrict__ mskP, const float* __restrict__ flow)
{
    constexpr int SYI = PH * 64;
    const int tid = threadIdx.x;
    const int id  = blockIdx.x;
    const int orig = (id & 7) * 128 + (id >> 3);   // 1024 blocks
    const int row = orig >> 1, gy = orig & 1;
    const int b = row >> 7, y = row & 127;
    const int o0 = gy * 256;

    const int wave = tid >> 6, lane = tid & 63;
    const int wm = wave >> 2, wn = wave & 3;
    const int l31 = lane & 31, lhi = lane >> 5;

    f32x16 acc[4] = {};

    const ushort* arow = actIn + ((size_t)b * PH + y) * SYI
                       + (wn * 32 + l31) * 64 + lhi * 8;
    const ushort* wb = wT3 + (o0 + wm * 128 + l31) * 16 + lhi * 8;

    #pragma unroll
    for (int tap = 0; tap < 9; ++tap) {
        const int ky = tap / 3, kx = tap % 3;
        #pragma unroll
        for (int ks = 0; ks < 4; ++ks) {
            const half8 bf = __builtin_bit_cast(half8,
                *(const short8*)&arow[ky * SYI + kx * 64 + ks * 16]);
            #pragma unroll
            for (int mg = 0; mg < 4; ++mg) {
                const half8 af = __builtin_bit_cast(half8,
                    *(const short8*)&wb[(size_t)(tap * 4 + ks) * 8192 + mg * 512]);
                acc[mg] = __builtin_amdgcn_mfma_f32_32x32x16_f16(af, bf, acc[mg], 0, 0, 0);
            }
        }
    }

    // ---- epilogue (packed fp16, as round 12) ----
    const int px = wn * 32 + l31;
    const size_t pixb = (size_t)y * WW + px;
    const float fl0 = flow[((size_t)b * 2)     * HWSZ + pixb];
    const float fl1 = flow[((size_t)b * 2 + 1) * HWSZ + pixb];
    uint*   offb = offP + (size_t)b * 144 * HWSZ;
    ushort* mskb = mskP + (size_t)b * 144 * HWSZ;
    #pragma unroll
    for (int mg = 0; mg < 4; ++mg) {
        #pragma unroll
        for (int t = 0; t < 8; ++t) {
            const int r0 = 2 * t;
            const int oc = o0 + wm * 128 + mg * 32 + (r0 & 3) + 8 * (r0 >> 2) + 4 * lhi;
            const float vy = acc[mg][r0]     + bias[oc < 432 ? oc : 0];
            const float vx = acc[mg][r0 + 1] + bias[oc < 431 ? oc + 1 : 0];
            if (oc < 288) {
                const float ry = 10.f * tanhf(vy) + fl1;
                const float rx = 10.f * tanhf(vx) + fl0;
                offb[(size_t)(oc >> 1) * HWSZ + pixb] =
                    (uint)f16_rn(ry) | ((uint)f16_rn(rx) << 16);
            } else if (oc < 432) {
                mskb[(size_t)(oc - 288) * HWSZ + pixb] = f16_rn(1.f / (1.f + expf(-vy)));
                mskb[(size_t)(oc - 287) * HWSZ + pixb] = f16_rn(1.f / (1.f + expf(-vx)));
            }
        }
    }
}

// ---------------------------------------------------------------------------
// MFMA deformable conv (round-12 v10, unchanged).
// ---------------------------------------------------------------------------
__global__ __launch_bounds__(256, 4) void deform_v10(
    const sh4* __restrict__ xP, const uint* __restrict__ offP,
    const ushort* __restrict__ mskP, const ushort* __restrict__ wdfh,
    const float* __restrict__ bias, float* __restrict__ outp)
{
    __shared__ float red[2][64][33];

    const int tid = threadIdx.x;
    const int id  = blockIdx.x;
    const int orig = (id & 7) * 256 + (id >> 3);
    const int x0 = (orig & 3) * 32;
    const int rl = orig >> 2;
    const int y = rl & 127, b = rl >> 7;

    const int wave = tid >> 6, lane = tid & 63;
    const int l31 = lane & 31, lhi = lane >> 5;
    const int k9h = wave >> 1;
    const int hv  = wave & 1;

    const int xp  = x0 + l31;
    const int pix = y * WW + xp;
    const uint*   offb = offP + (size_t)b * 144 * HWSZ;
    const ushort* mskb = mskP + (size_t)b * 144 * HWSZ;
    const float fy = (float)y, fx = (float)xp;

    f32x16 acc[2] = {};

    const int k9lo = k9h ? 5 : 0;
    const int k9hi = k9h ? 9 : 5;
    for (int k9 = k9lo; k9 < k9hi; ++k9) {
        const float kyf = (float)(k9 / 3 - 1);
        const float kxf = (float)(k9 % 3 - 1);
        #pragma unroll
        for (int ks = 0; ks < 2; ++ks) {
            short8 bfs;
            #pragma unroll
            for (int d2 = 0; d2 < 2; ++d2) {
                const int dg = hv * 8 + ks * 4 + lhi * 2 + d2;
                const int m  = dg * 9 + k9;
                const uint u = offb[(size_t)m * HWSZ + pix];
                const float dy = f16_f((ushort)(u & 0xffffu));
                const float dx = f16_f((ushort)(u >> 16));
                const float mk = f16_f(mskb[(size_t)m * HWSZ + pix]);
                const float py = dy + kyf + fy;
                const float px = dx + kxf + fx;
                const float y0f = floorf(py), x0f = floorf(px);
                const float ly = py - y0f, lx = px - x0f;
                const int yi = (int)y0f, xi = (int)x0f;
                const float w00 = (1.f - ly) * (1.f - lx), w01 = (1.f - ly) * lx;
                const float w10 = ly * (1.f - lx),         w11 = ly * lx;
                const bool vy0 = (unsigned)yi < (unsigned)HH, vy1 = (unsigned)(yi + 1) < (unsigned)HH;
                const bool vx0 = (unsigned)xi < (unsigned)WW, vx1 = (unsigned)(xi + 1) < (unsigned)WW;
                const float f00 = (vy0 && vx0) ? w00 * mk : 0.f;
                const float f01 = (vy0 && vx1) ? w01 * mk : 0.f;
                const float f10 = (vy1 && vx0) ? w10 * mk : 0.f;
                const float f11 = (vy1 && vx1) ? w11 * mk : 0.f;
                const int cy0 = min(max(yi, 0), HH - 1), cy1 = min(max(yi + 1, 0), HH - 1);
                const int cx0 = min(max(xi, 0), WW - 1), cx1 = min(max(xi + 1, 0), WW - 1);
                const sh4* xg = xP + (size_t)(b * 16 + dg) * HWSZ;
                const sh4 c00 = xg[cy0 * WW + cx0], c01 = xg[cy0 * WW + cx1];
                const sh4 c10 = xg[cy1 * WW + cx0], c11 = xg[cy1 * WW + cx1];
                #pragma unroll
                for (int n = 0; n < 4; ++n) {
                    const float s = f00 * f16_f((ushort)c00[n]) + f01 * f16_f((ushort)c01[n])
                                  + f10 * f16_f((ushort)c10[n]) + f11 * f16_f((ushort)c11[n]);
                    bfs[d2 * 4 + n] = (short)f16_rn(s);
                }
            }
            const half8 bf = __builtin_bit_cast(half8, bfs);
            const size_t abase = (size_t)((k9 * 2 + hv) * 2 + ks) * 1024 + l31 * 16 + lhi * 8;
            #pragma unroll
            for (int mg = 0; mg < 2; ++mg) {
                const half8 ah = __builtin_bit_cast(half8, *(const short8*)&wdfh[abase + mg * 512]);
                acc[mg] = __builtin_amdgcn_mfma_f32_32x32x16_f16(ah, bf, acc[mg], 0, 0, 0);
            }
        }
    }

    if (wave >= 2) {
        #pragma unroll
        for (int mg = 0; mg < 2; ++mg)
            #pragma unroll
            for (int r = 0; r < 16; ++r)
                red[wave - 2][lane][mg * 16 + r] = acc[mg][r];
    }
    __syncthreads();
    if (wave < 2) {
        #pragma unroll
        for (int mg = 0; mg < 2; ++mg)
            #pragma unroll
            for (int r = 0; r < 16; ++r)
                acc[mg][r] += red[wave][lane][mg * 16 + r];
    }
    __syncthreads();
    if (wave == 1) {
        #pragma unroll
        for (int mg = 0; mg < 2; ++mg)
            #pragma unroll
            for (int r = 0; r < 16; ++r)
                red[0][lane][mg * 16 + r] = acc[mg][r];
    }
    __syncthreads();
    if (wave == 0) {
        #pragma unroll
        for (int mg = 0; mg < 2; ++mg)
            #pragma unroll
            for (int r = 0; r < 16; ++r) {
                const int oc = mg * 32 + (r & 3) + 8 * (r >> 2) + 4 * lhi;
                const float v = acc[mg][r] + red[0][lane][mg * 16 + r] + bias[oc];
                outp[(((size_t)b * 64 + oc) * HH + y) * WW + xp] = v;
            }
    }
}

// ---------------------------------------------------------------------------
extern "C" void kernel_launch(void* const* d_in, const int* in_sizes, int n_in,
                              void* d_out, int out_size, void* d_ws, size_t ws_size,
                              hipStream_t stream) {
    const float* x    = (const float*)d_in[0];
    const float* xfw  = (const float*)d_in[1];
    const float* xcur = (const float*)d_in[2];
    const float* flow = (const float*)d_in[3];
    const float* w0   = (const float*)d_in[4];
    const float* b0   = (const float*)d_in[5];
    const float* w1   = (const float*)d_in[6];
    const float* b1   = (const float*)d_in[7];
    const float* w2   = (const float*)d_in[8];
    const float* b2   = (const float*)d_in[9];
    const float* w3   = (const float*)d_in[10];
    const float* b3   = (const float*)d_in[11];
    const float* wdcn = (const float*)d_in[12];
    const float* bdcn = (const float*)d_in[13];
    float* out = (float*)d_out;

    // workspace layout (all 16B-aligned):
    char* p = (char*)d_ws;
    uint*   offP    = (uint*)p;                         p += (size_t)BB * 144 * HWSZ * 4;   // 37.7MB
    ushort* mskP    = (ushort*)p;                       p += (size_t)BB * 144 * HWSZ * 2;   // 18.9MB
    ushort* h0A     = (ushort*)p;                       p += (size_t)BB * PH * PH * 64 * 2; // 8.65MB
    ushort* h1A     = (ushort*)p;                       p += (size_t)BB * PH * PH * 64 * 2; // 8.65MB
    ushort* concatA = (ushort*)p;                       p += (size_t)BB * PH * PH * 144 * 2;// 19.5MB
    sh4*    xPh     = (sh4*)p;                          p += (size_t)BB * 16 * HWSZ * 8;    // 8.4MB
    ushort* wdh = (ushort*)p;                           p += 64 * 576 * 2;
    ushort* w0T = (ushort*)p;                           p += 9 * 9 * 64 * 16 * 2;
    ushort* w1T = (ushort*)p;                           p += 9 * 4 * 64 * 16 * 2;
    ushort* w2T = (ushort*)p;                           p += 9 * 4 * 64 * 16 * 2;
    ushort* w3T = (ushort*)p;                           p += 36 * 512 * 16 * 2;
    ushort* h2A = h0A;   // conv2 output reuses h0A (h0A dead after conv1)

    // zero padded activation buffers (borders must be 0)
    hipMemsetAsync(concatA, 0, (size_t)BB * PH * PH * 144 * 2, stream);
    hipMemsetAsync(h0A,     0, (size_t)BB * PH * PH * 64 * 2,  stream);
    hipMemsetAsync(h1A,     0, (size_t)BB * PH * PH * 64 * 2,  stream);

    prep_wcm<<<dim3((9 * 9 * 64 * 16 + 255) / 256), dim3(256), 0, stream>>>(w0, w0T, 130, 144);
    prep_wcm<<<dim3((9 * 4 * 64 * 16 + 255) / 256), dim3(256), 0, stream>>>(w1, w1T, 64, 64);
    prep_wcm<<<dim3((9 * 4 * 64 * 16 + 255) / 256), dim3(256), 0, stream>>>(w2, w2T, 64, 64);
    prep_w3cm<<<dim3((36 * 512 * 16 + 255) / 256), dim3(256), 0, stream>>>(w3, w3T);
    prep_wdf_k<<<dim3((64 * 576 + 255) / 256), dim3(256), 0, stream>>>(wdcn, wdh);
    cvt_cm<<<dim3(BB * HH), dim3(256), 0, stream>>>(xfw, xcur, flow, concatA);
    pack_x_k<<<dim3((BB * 16 * HWSZ + 255) / 256), dim3(256), 0, stream>>>(x, xPh);

    conv_cm<144, 9><<<dim3(BB * HH), dim3(512), 0, stream>>>(concatA, w0T, b0, h0A);
    conv_cm<64, 4><<<dim3(BB * HH), dim3(512), 0, stream>>>(h0A, w1T, b1, h1A);
    conv_cm<64, 4><<<dim3(BB * HH), dim3(512), 0, stream>>>(h1A, w2T, b2, h2A);
    conv3_cm<<<dim3(BB * HH * 2), dim3(512), 0, stream>>>(h2A, w3T, b3, offP, mskP, flow);

    deform_v10<<<dim3(2048), dim3(256), 0, stream>>>(xPh, offP, mskP, wdh, bdcn, out);
}